// Round 4
// baseline (115.277 us; speedup 1.0000x reference)
//
#include <hip/hip_runtime.h>
#include <hip/hip_bf16.h>

typedef __attribute__((ext_vector_type(8))) __bf16 bf16x8;
typedef __attribute__((ext_vector_type(4))) float  f32x4;

constexpr int NROW = 8192;
constexpr int DDIM = 256;
constexpr int KDIM = 512;               // packed [x | e]
constexpr int BM = 256, BN = 128, BK = 32;
constexpr int NT = KDIM / BK;           // 16 K-tiles
constexpr int ABYTES = BM * BK * 2;     // 16 KB
constexpr int BBYTES = BN * BK * 2;     // 8 KB
constexpr int BUFBYTES = ABYTES + BBYTES; // 24 KB; x2 = 48 KB total LDS

__device__ __forceinline__ void gload_lds16(const void* g, void* l) {
  __builtin_amdgcn_global_load_lds(
      (const __attribute__((address_space(1))) void*)g,
      (__attribute__((address_space(3))) void*)l, 16, 0, 0);
}

// ---------------- prep: P = [bf16(x) | bf16(exp(1-dc))], s_i = (1-p)/d*|x_i|^2
__global__ __launch_bounds__(256) void prep_kernel(
    const float* __restrict__ x, const float* __restrict__ dc,
    const float* __restrict__ pparm,
    __hip_bfloat16* __restrict__ P, float* __restrict__ s)
{
  const int row = blockIdx.x;
  const int t   = threadIdx.x;
  const float xv = x[(size_t)row * DDIM + t];
  const float ev = __expf(1.0f - dc[(size_t)row * DDIM + t]);
  P[(size_t)row * KDIM + t]        = __float2bfloat16(xv);
  P[(size_t)row * KDIM + DDIM + t] = __float2bfloat16(ev);

  float v = xv * xv;
  #pragma unroll
  for (int off = 32; off > 0; off >>= 1) v += __shfl_down(v, off, 64);
  __shared__ float red[4];
  const int lane = t & 63, wid = t >> 6;
  if (lane == 0) red[wid] = v;
  __syncthreads();
  if (t == 0) {
    const float p = pparm[0];
    s[row] = (1.0f - p) * (1.0f / (float)DDIM) * (red[0] + red[1] + red[2] + red[3]);
  }
}

// ---------------- GEMM: G = P@P^T segment-scaled; sim = 1/(s_i+s_j+ce*G), diag=1
// 256x128 tile, 8 waves (4M x 2N), per-wave 64x64, BK=32, dbuf + counted prefetch.
// 48 KB LDS + <=128 VGPR -> 2 blocks/CU: cross-block overlap of epilogue/prologue.
__global__ void __launch_bounds__(512, 4) adj_gemm(
    const __hip_bfloat16* __restrict__ P, const float* __restrict__ s,
    const float* __restrict__ pparm, float* __restrict__ out)
{
  __shared__ __align__(16) char lds[2 * BUFBYTES];

  const float p  = pparm[0];
  const float cx = -2.0f * (1.0f - p) / (float)DDIM;
  const float ce = p / (float)DDIM;
  const float midscale = cx / ce;

  // XCD swizzle: 2048 blocks = 8 XCDs x 256; XCD owns bi band of 4 (1 MB A in L2).
  const int orig  = blockIdx.x;
  const int xcd   = orig & 7;
  const int local = orig >> 3;             // 0..255
  const int bi = xcd * 4 + (local & 3);    // 0..31
  const int bj = local >> 2;               // 0..63
  const int rowBase = bi * BM;
  const int colBase = bj * BN;

  const int tid  = threadIdx.x;
  const int lane = tid & 63;
  const int wid  = tid >> 6;               // 8 waves: wm = wid>>1 (4), wn = wid&1 (2)
  const int wmrow = (wid >> 1) * 64;
  const int wnrow = (wid & 1) * 64;
  const int frow = lane & 15;
  const int kq   = lane >> 4;

  // read swizzle: LDS byte (r,c) holds logical (r, c ^ ((r&3)<<4)); row = 64 B.
  const int cb = (kq * 16) ^ ((frow & 3) << 4);

  // staging: per thread 2 A-chunks + 1 B-chunk of 16 B; linear LDS dest,
  // pre-swizzled global source (involution; rule 21).
  const int rA0  = tid >> 2;               // 0..127 (A1: +128; B: same row idx)
  const int gcol = ((tid & 3) * 16) ^ ((rA0 & 3) << 4);
  const char* Pc = (const char*)P;
  const char* gA0 = Pc + (size_t)(rowBase + rA0)       * (KDIM * 2) + gcol;
  const char* gA1 = Pc + (size_t)(rowBase + 128 + rA0) * (KDIM * 2) + gcol;
  const char* gB  = Pc + (size_t)(colBase + rA0)       * (KDIM * 2) + gcol;
  const int dA0 = tid * 16, dA1 = 8192 + tid * 16, dB = ABYTES + tid * 16;

#define STAGE(kk) do {                                   \
    char* _b = lds + ((kk) & 1) * BUFBYTES;              \
    const int _ko = (kk) * (BK * 2);                     \
    gload_lds16(gA0 + _ko, _b + dA0);                    \
    gload_lds16(gA1 + _ko, _b + dA1);                    \
    gload_lds16(gB  + _ko, _b + dB);                     \
  } while (0)

  // prologue
  STAGE(0);
  asm volatile("s_waitcnt vmcnt(0)" ::: "memory");
  asm volatile("s_barrier" ::: "memory");

  f32x4 acc[4][4];
  #pragma unroll
  for (int m = 0; m < 4; ++m)
    #pragma unroll
    for (int n = 0; n < 4; ++n)
      acc[m][n] = (f32x4){0.f, 0.f, 0.f, 0.f};

  #pragma unroll
  for (int t = 0; t < NT; ++t) {
    const char* buf  = lds + (t & 1) * BUFBYTES;
    const char* bufB = buf + ABYTES;

    if (t < NT - 1) STAGE(t + 1);          // issue next tile first (T3-min recipe)

    bf16x8 a[4], b[4];
    #pragma unroll
    for (int i = 0; i < 4; ++i)
      a[i] = *(const bf16x8*)(buf + (wmrow + i * 16 + frow) * 64 + cb);
    #pragma unroll
    for (int j = 0; j < 4; ++j)
      b[j] = *(const bf16x8*)(bufB + (wnrow + j * 16 + frow) * 64 + cb);

    #pragma unroll
    for (int i = 0; i < 4; ++i)
      #pragma unroll
      for (int j = 0; j < 4; ++j)
        acc[i][j] = __builtin_amdgcn_mfma_f32_16x16x32_bf16(a[i], b[j], acc[i][j], 0, 0, 0);

    if (t == DDIM / BK - 1) {              // x-segment done: acc = Sx -> * cx/ce
      #pragma unroll
      for (int m = 0; m < 4; ++m)
        #pragma unroll
        for (int n = 0; n < 4; ++n)
          acc[m][n] *= midscale;
    }

    if (t < NT - 1) {
      asm volatile("s_waitcnt vmcnt(0)" ::: "memory");   // next tile landed
      asm volatile("s_barrier" ::: "memory");
    }
  }

  // ---- epilogue: denom = s_i + s_j + ce*acc ; out = 1/denom (diag = 1)
  const int rq = lane >> 4;
  #pragma unroll
  for (int n = 0; n < 4; ++n) {
    const int gcol_o = colBase + wnrow + n * 16 + frow;
    const float scol = s[gcol_o];
    #pragma unroll
    for (int m = 0; m < 4; ++m) {
      const int growb = rowBase + wmrow + m * 16 + rq * 4;
      #pragma unroll
      for (int r = 0; r < 4; ++r) {
        const int grow = growb + r;
        const float denom = s[grow] + scol + ce * acc[m][n][r];
        const float val = (grow == gcol_o) ? 1.0f : __builtin_amdgcn_rcpf(denom);
        out[(size_t)grow * NROW + gcol_o] = val;
      }
    }
  }
}

extern "C" void kernel_launch(void* const* d_in, const int* in_sizes, int n_in,
                              void* d_out, int out_size, void* d_ws, size_t ws_size,
                              hipStream_t stream) {
  const float* x  = (const float*)d_in[0];
  const float* dc = (const float*)d_in[1];
  const float* pp = (const float*)d_in[2];
  float* out = (float*)d_out;

  __hip_bfloat16* P = (__hip_bfloat16*)d_ws;                       // 8 MB
  float* s = (float*)((char*)d_ws + (size_t)NROW * KDIM * 2);      // +32 KB

  prep_kernel<<<NROW, 256, 0, stream>>>(x, dc, pp, P, s);
  adj_gemm<<<(NROW / BM) * (NROW / BN), 512, 0, stream>>>(P, s, pp, out);
}